// Round 8
// baseline (381.346 us; speedup 1.0000x reference)
//
#include <hip/hip_runtime.h>

#define SEQ   2048
#define NHEAD 16
#define HD    64
#define HID   1024
#define NQKV  1152
#define MROWS 4096  // B*S

typedef unsigned short u16;
typedef unsigned int u32;
typedef __attribute__((ext_vector_type(8))) __bf16 bfrag;
typedef __attribute__((ext_vector_type(4))) float f32x4;
typedef __attribute__((ext_vector_type(4))) short s16x4;

__device__ __forceinline__ u16 f2bf(float f) {
  unsigned u = __float_as_uint(f);
  u += 0x7fffu + ((u >> 16) & 1u);
  return (u16)(u >> 16);
}

// ---------- converts ----------
__global__ void k_cvt_x(const float* __restrict__ x, u16* __restrict__ o) {
  int i = (blockIdx.x * 256 + threadIdx.x) * 4;
  float4 v = *reinterpret_cast<const float4*>(x + i);
  s16x4 r;
  r.x = (short)f2bf(v.x); r.y = (short)f2bf(v.y);
  r.z = (short)f2bf(v.z); r.w = (short)f2bf(v.w);
  *reinterpret_cast<s16x4*>(o + i) = r;
}

// tiled transpose+convert: dst[nOff+n][k] = src[k][n]  (dst row stride 1024)
__global__ void k_tr(const float* __restrict__ src, int ld, u16* __restrict__ dst, int nOff) {
  __shared__ float T[64][65];
  const int t = threadIdx.x;
  const int k0 = blockIdx.x * 64, n0 = blockIdx.y * 64;
#pragma unroll
  for (int p = 0; p < 4; ++p) {
    int r = p * 16 + (t >> 4), c = (t & 15) * 4;
    float4 v = *reinterpret_cast<const float4*>(&src[(size_t)(k0 + r) * ld + n0 + c]);
    T[r][c] = v.x; T[r][c + 1] = v.y; T[r][c + 2] = v.z; T[r][c + 3] = v.w;
  }
  __syncthreads();
#pragma unroll
  for (int p = 0; p < 2; ++p) {
    int cc = t + p * 256;
    int n = cc >> 3, k8 = (cc & 7) * 8;
    union { float4 v; u16 u[8]; } o;
#pragma unroll
    for (int j = 0; j < 8; ++j) o.u[j] = f2bf(T[k8 + j][n]);
    *reinterpret_cast<float4*>(&dst[(size_t)(nOff + n0 + n) * 1024 + k0 + k8]) = o.v;
  }
}

__global__ void k_bias(const float* __restrict__ bq, const float* __restrict__ bk,
                       const float* __restrict__ bv, float* __restrict__ bqkv) {
  int t = blockIdx.x * 256 + threadIdx.x;
  if (t >= NQKV) return;
  float v;
  if (t < 1024)      v = bq[t];
  else if (t < 1088) v = bk[t - 1024];
  else               v = bv[t - 1088];
  bqkv[t] = v;
}

__global__ void k_mb(const int* __restrict__ am, float* __restrict__ Mbias) {
  int t = blockIdx.x * 256 + threadIdx.x;
  if (t < 2 * SEQ) Mbias[t] = am[t] ? 0.0f : -1e30f;
}

// Vt[b][d][s] = V[b][s][d] via LDS-tiled transpose (64 s-rows per block)
__global__ void k_vt(const u16* __restrict__ QKV, u16* __restrict__ Vt) {
  __shared__ u16 T[64][72];
  const int t = threadIdx.x;
  const int s0 = blockIdx.x * 64, b = blockIdx.y;
  // load 64 rows x 64 d (each row = 8 chunks of 16B), coalesced
#pragma unroll
  for (int p = 0; p < 2; ++p) {
    int c = t + p * 256;                 // 512 chunks
    int r = c >> 3, ch = c & 7;
    *reinterpret_cast<float4*>(&T[r][ch * 8]) = *reinterpret_cast<const float4*>(
        &QKV[(size_t)(b * SEQ + s0 + r) * NQKV + 1088 + ch * 8]);
  }
  __syncthreads();
  // write 64 d-rows x 64 s, coalesced (gather columns from LDS)
#pragma unroll
  for (int p = 0; p < 2; ++p) {
    int cc = t + p * 256;                // 512 chunks
    int d = cc >> 3, sc = cc & 7;
    union { float4 v; u16 u[8]; } o;
#pragma unroll
    for (int j = 0; j < 8; ++j) o.u[j] = T[sc * 8 + j][d];
    *reinterpret_cast<float4*>(&Vt[((size_t)b * 64 + d) * SEQ + s0 + sc * 8]) = o.v;
  }
}

// ---------- GEMM v2: 128x64 tile, BK=64, XOR-swizzled LDS (r4, proven) ----------
template <int STORE_BF16>
__global__ __launch_bounds__(256) void k_gemm(const u16* __restrict__ A,
                                              const u16* __restrict__ Bt,
                                              const float* __restrict__ bias,
                                              void* __restrict__ Cout,
                                              int M, int N, int K) {
  __shared__ __align__(16) u16 Al[128 * 64];
  __shared__ __align__(16) u16 Bl[64 * 64];
  const int tid = threadIdx.x;
  const int lane = tid & 63, l16 = lane & 15, lg = lane >> 4;
  const int wid = tid >> 6;
  const int m0 = blockIdx.x * 128, n0 = blockIdx.y * 64;
  f32x4 acc[2][4] = {};
  for (int k0 = 0; k0 < K; k0 += 64) {
#pragma unroll
    for (int p = 0; p < 4; ++p) {
      int c = tid + p * 256;            // 1024 chunks of 16B (A tile)
      int r = c >> 3, sl = c & 7;
      __builtin_amdgcn_global_load_lds(
          (__attribute__((address_space(1))) void*)(A + (size_t)(m0 + r) * K + k0 + ((sl ^ (r & 7)) << 3)),
          (__attribute__((address_space(3))) void*)(Al + c * 8), 16, 0, 0);
    }
#pragma unroll
    for (int p = 0; p < 2; ++p) {
      int c = tid + p * 256;            // 512 chunks of 16B (B tile)
      int r = c >> 3, sl = c & 7;
      __builtin_amdgcn_global_load_lds(
          (__attribute__((address_space(1))) void*)(Bt + (size_t)(n0 + r) * K + k0 + ((sl ^ (r & 7)) << 3)),
          (__attribute__((address_space(3))) void*)(Bl + c * 8), 16, 0, 0);
    }
    __syncthreads();
#pragma unroll
    for (int kk = 0; kk < 2; ++kk) {
      bfrag a[2], b[4];
#pragma unroll
      for (int mi = 0; mi < 2; ++mi) {
        int row = wid * 32 + mi * 16 + l16;
        a[mi] = *reinterpret_cast<const bfrag*>(
            Al + row * 64 + ((((kk << 2) | lg) ^ (l16 & 7)) << 3));
      }
#pragma unroll
      for (int ni = 0; ni < 4; ++ni) {
        int row = ni * 16 + l16;
        b[ni] = *reinterpret_cast<const bfrag*>(
            Bl + row * 64 + ((((kk << 2) | lg) ^ (l16 & 7)) << 3));
      }
#pragma unroll
      for (int mi = 0; mi < 2; ++mi)
#pragma unroll
        for (int ni = 0; ni < 4; ++ni)
          acc[mi][ni] = __builtin_amdgcn_mfma_f32_16x16x32_bf16(a[mi], b[ni], acc[mi][ni], 0, 0, 0);
    }
    __syncthreads();
  }
#pragma unroll
  for (int mi = 0; mi < 2; ++mi)
#pragma unroll
    for (int ni = 0; ni < 4; ++ni) {
      int col = n0 + ni * 16 + l16;
      float bb = bias[col];
#pragma unroll
      for (int r = 0; r < 4; ++r) {
        int row = m0 + wid * 32 + mi * 16 + lg * 4 + r;
        float v = acc[mi][ni][r] + bb;
        if (STORE_BF16) ((u16*)Cout)[(size_t)row * N + col] = f2bf(v);
        else            ((float*)Cout)[(size_t)row * N + col] = v;
      }
    }
}

// ---------- flash attention: BARRIER-FREE (r7 minus LDS staging) ----------
// grid (S/64, NHEAD, B), 4 waves; wave = 16 query rows; 128 kv rows / iter.
// Swapped QK^T: scores rows = kv (lg*4+r), cols = q (l16).
// K fragments read directly from L2 (same values the r7 swizzled-LDS path
// produced: chunk lg and chunk 4+lg of each K row). Zero __syncthreads.
__global__ __launch_bounds__(256, 2) void k_attn(const u16* __restrict__ QKV,
                                                 const u16* __restrict__ Vt,
                                                 const float* __restrict__ Mbias,
                                                 u16* __restrict__ ctx) {
  __shared__ __align__(16) u16 Pl[4][2][16][72];  // 18 KB, wave-private P (two halves)
  const int tid = threadIdx.x;
  const int lane = tid & 63, l16 = lane & 15, lg = lane >> 4, wid = tid >> 6;
  const int q0 = blockIdx.x * 64 + wid * 16;
  const int h = blockIdx.y, b = blockIdx.z;

  const u16* Qrow = QKV + (size_t)(b * SEQ + q0 + l16) * NQKV + h * 64;
  const bfrag aq0 = *reinterpret_cast<const bfrag*>(Qrow + lg * 8);
  const bfrag aq1 = *reinterpret_cast<const bfrag*>(Qrow + 32 + lg * 8);
  const u16* Vb = Vt + (size_t)b * 64 * SEQ;
  const u16* Kg = QKV + (size_t)b * SEQ * NQKV + HID;  // K rows, stride NQKV
  const float* mb = Mbias + b * SEQ;

  float mrun = -1e30f, lrun = 0.0f;  // softmax state for q = l16
  f32x4 accO[4] = {};                // rows q = lg*4+r, cols d = nt*16+l16

  for (int it = 0; it < SEQ / 128; ++it) {
    const int kv0 = it * 128;

    // V prefetch, half A: B-frag rows d = nt*16+l16, k = kv0+kb*32+lg*8
    bfrag vfA[4][2];
#pragma unroll
    for (int nt = 0; nt < 4; ++nt)
#pragma unroll
      for (int kb = 0; kb < 2; ++kb)
        vfA[nt][kb] = *reinterpret_cast<const bfrag*>(
            Vb + (size_t)(nt * 16 + l16) * SEQ + kv0 + kb * 32 + lg * 8);

    // QK^T for both 64-row tiles, K fragments direct from L2
    f32x4 s[8];
#pragma unroll
    for (int half = 0; half < 2; ++half)
#pragma unroll
      for (int nt = 0; nt < 4; ++nt) {
        const u16* krow = Kg + (size_t)(kv0 + half * 64 + nt * 16 + l16) * NQKV;
        bfrag ak0 = *reinterpret_cast<const bfrag*>(krow + lg * 8);
        bfrag ak1 = *reinterpret_cast<const bfrag*>(krow + 32 + lg * 8);
        f32x4 z = {};
        z = __builtin_amdgcn_mfma_f32_16x16x32_bf16(ak0, aq0, z, 0, 0, 0);
        z = __builtin_amdgcn_mfma_f32_16x16x32_bf16(ak1, aq1, z, 0, 0, 0);
        s[half * 4 + nt] = z;
      }

    // scale + mask bias (L2-resident broadcast reads)
#pragma unroll
    for (int i8 = 0; i8 < 8; ++i8) {
      f32x4 mbv = *reinterpret_cast<const f32x4*>(&mb[kv0 + i8 * 16 + lg * 4]);
#pragma unroll
      for (int r = 0; r < 4; ++r)
        s[i8][r] = s[i8][r] * 0.125f + mbv[r];
    }
    // max over 128 kv: 31 in-lane + xor16 + xor32
    float tm[8];
#pragma unroll
    for (int i8 = 0; i8 < 8; ++i8)
      tm[i8] = fmaxf(fmaxf(s[i8][0], s[i8][1]), fmaxf(s[i8][2], s[i8][3]));
    float tmax = fmaxf(fmaxf(fmaxf(tm[0], tm[1]), fmaxf(tm[2], tm[3])),
                       fmaxf(fmaxf(tm[4], tm[5]), fmaxf(tm[6], tm[7])));
    tmax = fmaxf(tmax, __shfl_xor(tmax, 16));
    tmax = fmaxf(tmax, __shfl_xor(tmax, 32));

    // defer-max (T13): rescale only when running max moved by > 8 nats
    if (!__all(tmax - mrun <= 8.0f)) {
      float mnew = fmaxf(mrun, tmax);
      float alpha = __expf(mrun - mnew);
      mrun = mnew;
      lrun *= alpha;
      float ar[4];
#pragma unroll
      for (int r = 0; r < 4; ++r) ar[r] = __shfl(alpha, lg * 4 + r);
#pragma unroll
      for (int nt = 0; nt < 4; ++nt)
#pragma unroll
        for (int r = 0; r < 4; ++r) accO[nt][r] *= ar[r];
    }

    // exp + row-sum over all 128
    float ps[8];
#pragma unroll
    for (int i8 = 0; i8 < 8; ++i8) {
#pragma unroll
      for (int r = 0; r < 4; ++r)
        s[i8][r] = __expf(s[i8][r] - mrun);
      ps[i8] = (s[i8][0] + s[i8][1]) + (s[i8][2] + s[i8][3]);
    }
    float rsum = ((ps[0] + ps[1]) + (ps[2] + ps[3])) + ((ps[4] + ps[5]) + (ps[6] + ps[7]));
    rsum += __shfl_xor(rsum, 16);
    rsum += __shfl_xor(rsum, 32);
    lrun += rsum;

    // ---- half A: P write -> vfB prefetch -> PV with vfA ----
#pragma unroll
    for (int nt = 0; nt < 4; ++nt)
#pragma unroll
      for (int r = 0; r < 4; ++r)
        Pl[wid][0][l16][nt * 16 + lg * 4 + r] = f2bf(s[nt][r]);
    bfrag vfB[4][2];
#pragma unroll
    for (int nt = 0; nt < 4; ++nt)
#pragma unroll
      for (int kb = 0; kb < 2; ++kb)
        vfB[nt][kb] = *reinterpret_cast<const bfrag*>(
            Vb + (size_t)(nt * 16 + l16) * SEQ + kv0 + 64 + kb * 32 + lg * 8);
    {
      bfrag ap0 = *reinterpret_cast<const bfrag*>(&Pl[wid][0][l16][lg * 8]);
      bfrag ap1 = *reinterpret_cast<const bfrag*>(&Pl[wid][0][l16][32 + lg * 8]);
#pragma unroll
      for (int nt = 0; nt < 4; ++nt) {
        accO[nt] = __builtin_amdgcn_mfma_f32_16x16x32_bf16(ap0, vfA[nt][0], accO[nt], 0, 0, 0);
        accO[nt] = __builtin_amdgcn_mfma_f32_16x16x32_bf16(ap1, vfA[nt][1], accO[nt], 0, 0, 0);
      }
    }
    // ---- half B: separate P buffer -> PV with vfB ----
#pragma unroll
    for (int nt = 0; nt < 4; ++nt)
#pragma unroll
      for (int r = 0; r < 4; ++r)
        Pl[wid][1][l16][nt * 16 + lg * 4 + r] = f2bf(s[4 + nt][r]);
    {
      bfrag ap0 = *reinterpret_cast<const bfrag*>(&Pl[wid][1][l16][lg * 8]);
      bfrag ap1 = *reinterpret_cast<const bfrag*>(&Pl[wid][1][l16][32 + lg * 8]);
#pragma unroll
      for (int nt = 0; nt < 4; ++nt) {
        accO[nt] = __builtin_amdgcn_mfma_f32_16x16x32_bf16(ap0, vfB[nt][0], accO[nt], 0, 0, 0);
        accO[nt] = __builtin_amdgcn_mfma_f32_16x16x32_bf16(ap1, vfB[nt][1], accO[nt], 0, 0, 0);
      }
    }
  }

  float linv = 1.0f / lrun;
  float lr[4];
#pragma unroll
  for (int r = 0; r < 4; ++r) lr[r] = __shfl(linv, lg * 4 + r);
#pragma unroll
  for (int nt = 0; nt < 4; ++nt)
#pragma unroll
    for (int r = 0; r < 4; ++r)
      ctx[(size_t)(b * SEQ + q0 + lg * 4 + r) * HID + h * 64 + nt * 16 + l16] =
          f2bf(accO[nt][r] * lr[r]);
}

extern "C" void kernel_launch(void* const* d_in, const int* in_sizes, int n_in,
                              void* d_out, int out_size, void* d_ws, size_t ws_size,
                              hipStream_t stream) {
  const float* x  = (const float*)d_in[0];
  const int* am   = (const int*)d_in[1];
  const float* Wq = (const float*)d_in[2];
  const float* bq = (const float*)d_in[3];
  const float* Wk = (const float*)d_in[4];
  const float* bk = (const float*)d_in[5];
  const float* Wv = (const float*)d_in[6];
  const float* bv = (const float*)d_in[7];
  const float* Wo = (const float*)d_in[8];
  const float* bo = (const float*)d_in[9];

  char* ws = (char*)d_ws;
  u16*  Xb     = (u16*)(ws + 0);          //  8.00 MB  [4096][1024]
  u16*  Wt_qkv = (u16*)(ws + 8388608);    //  2.25 MB  [1152][1024]
  u16*  Wt_o   = (u16*)(ws + 10747904);   //  2.00 MB  [1024][1024]
  float* bqkv  = (float*)(ws + 12845056); //  4.5 KB
  float* Mbias = (float*)(ws + 12849664); // 16 KB    [2][2048]
  u16*  QKV    = (u16*)(ws + 12866048);   //  9.00 MB  [4096][1152]
  u16*  Vt     = (u16*)(ws + 22303232);   //  0.50 MB  [2][64][2048]
  u16*  ctx    = (u16*)(ws + 22827520);   //  8.00 MB  [4096][1024]

  k_cvt_x<<<4096, 256, 0, stream>>>(x, Xb);
  k_tr<<<dim3(16, 16), 256, 0, stream>>>(Wq, 1024, Wt_qkv, 0);
  k_tr<<<dim3(16, 1), 256, 0, stream>>>(Wk, 64, Wt_qkv, 1024);
  k_tr<<<dim3(16, 1), 256, 0, stream>>>(Wv, 64, Wt_qkv, 1088);
  k_tr<<<dim3(16, 16), 256, 0, stream>>>(Wo, 1024, Wt_o, 0);
  k_bias<<<5, 256, 0, stream>>>(bq, bk, bv, bqkv);
  k_mb<<<16, 256, 0, stream>>>(am, Mbias);

  dim3 g1(32, 18);
  k_gemm<1><<<g1, 256, 0, stream>>>(Xb, Wt_qkv, bqkv, (void*)QKV, MROWS, NQKV, HID);

  k_vt<<<dim3(32, 2), 256, 0, stream>>>(QKV, Vt);

  dim3 g2(SEQ / 64, NHEAD, 2);
  k_attn<<<g2, 256, 0, stream>>>(QKV, Vt, Mbias, ctx);

  dim3 g3(32, 16);
  k_gemm<0><<<g3, 256, 0, stream>>>(ctx, Wt_o, bo, d_out, MROWS, HID, HID);
}

// Round 9
// 225.187 us; speedup vs baseline: 1.6935x; 1.6935x over previous
//
#include <hip/hip_runtime.h>

#define SEQ   2048
#define NHEAD 16
#define HD    64
#define HID   1024
#define NQKV  1152
#define MROWS 4096  // B*S

typedef unsigned short u16;
typedef unsigned int u32;
typedef __attribute__((ext_vector_type(8))) __bf16 bfrag;
typedef __attribute__((ext_vector_type(4))) float f32x4;
typedef __attribute__((ext_vector_type(16))) float f32x16;
typedef __attribute__((ext_vector_type(4))) short s16x4;

__device__ __forceinline__ u16 f2bf(float f) {
  unsigned u = __float_as_uint(f);
  u += 0x7fffu + ((u >> 16) & 1u);
  return (u16)(u >> 16);
}

__device__ __forceinline__ u32 cvtpk_bf16(float lo, float hi) {
  u32 r;
  asm("v_cvt_pk_bf16_f32 %0, %1, %2" : "=v"(r) : "v"(lo), "v"(hi));
  return r;
}

// ---------- converts ----------
__global__ void k_cvt_x(const float* __restrict__ x, u16* __restrict__ o) {
  int i = (blockIdx.x * 256 + threadIdx.x) * 4;
  float4 v = *reinterpret_cast<const float4*>(x + i);
  s16x4 r;
  r.x = (short)f2bf(v.x); r.y = (short)f2bf(v.y);
  r.z = (short)f2bf(v.z); r.w = (short)f2bf(v.w);
  *reinterpret_cast<s16x4*>(o + i) = r;
}

// tiled transpose+convert: dst[nOff+n][k] = src[k][n]  (dst row stride 1024)
__global__ void k_tr(const float* __restrict__ src, int ld, u16* __restrict__ dst, int nOff) {
  __shared__ float T[64][65];
  const int t = threadIdx.x;
  const int k0 = blockIdx.x * 64, n0 = blockIdx.y * 64;
#pragma unroll
  for (int p = 0; p < 4; ++p) {
    int r = p * 16 + (t >> 4), c = (t & 15) * 4;
    float4 v = *reinterpret_cast<const float4*>(&src[(size_t)(k0 + r) * ld + n0 + c]);
    T[r][c] = v.x; T[r][c + 1] = v.y; T[r][c + 2] = v.z; T[r][c + 3] = v.w;
  }
  __syncthreads();
#pragma unroll
  for (int p = 0; p < 2; ++p) {
    int cc = t + p * 256;
    int n = cc >> 3, k8 = (cc & 7) * 8;
    union { float4 v; u16 u[8]; } o;
#pragma unroll
    for (int j = 0; j < 8; ++j) o.u[j] = f2bf(T[k8 + j][n]);
    *reinterpret_cast<float4*>(&dst[(size_t)(nOff + n0 + n) * 1024 + k0 + k8]) = o.v;
  }
}

__global__ void k_bias(const float* __restrict__ bq, const float* __restrict__ bk,
                       const float* __restrict__ bv, float* __restrict__ bqkv) {
  int t = blockIdx.x * 256 + threadIdx.x;
  if (t >= NQKV) return;
  float v;
  if (t < 1024)      v = bq[t];
  else if (t < 1088) v = bk[t - 1024];
  else               v = bv[t - 1088];
  bqkv[t] = v;
}

__global__ void k_mb(const int* __restrict__ am, float* __restrict__ Mbias) {
  int t = blockIdx.x * 256 + threadIdx.x;
  if (t < 2 * SEQ) Mbias[t] = am[t] ? 0.0f : -1e30f;
}

// Vt[b][d][s] = V[b][s][d] via LDS-tiled transpose (64 s-rows per block)
__global__ void k_vt(const u16* __restrict__ QKV, u16* __restrict__ Vt) {
  __shared__ u16 T[64][72];
  const int t = threadIdx.x;
  const int s0 = blockIdx.x * 64, b = blockIdx.y;
#pragma unroll
  for (int p = 0; p < 2; ++p) {
    int c = t + p * 256;                 // 512 chunks
    int r = c >> 3, ch = c & 7;
    *reinterpret_cast<float4*>(&T[r][ch * 8]) = *reinterpret_cast<const float4*>(
        &QKV[(size_t)(b * SEQ + s0 + r) * NQKV + 1088 + ch * 8]);
  }
  __syncthreads();
#pragma unroll
  for (int p = 0; p < 2; ++p) {
    int cc = t + p * 256;                // 512 chunks
    int d = cc >> 3, sc = cc & 7;
    union { float4 v; u16 u[8]; } o;
#pragma unroll
    for (int j = 0; j < 8; ++j) o.u[j] = T[sc * 8 + j][d];
    *reinterpret_cast<float4*>(&Vt[((size_t)b * 64 + d) * SEQ + s0 + sc * 8]) = o.v;
  }
}

// ---------- GEMM v2: 128x64 tile, BK=64, XOR-swizzled LDS (r4, proven) ----------
template <int STORE_BF16>
__global__ __launch_bounds__(256) void k_gemm(const u16* __restrict__ A,
                                              const u16* __restrict__ Bt,
                                              const float* __restrict__ bias,
                                              void* __restrict__ Cout,
                                              int M, int N, int K) {
  __shared__ __align__(16) u16 Al[128 * 64];
  __shared__ __align__(16) u16 Bl[64 * 64];
  const int tid = threadIdx.x;
  const int lane = tid & 63, l16 = lane & 15, lg = lane >> 4;
  const int wid = tid >> 6;
  const int m0 = blockIdx.x * 128, n0 = blockIdx.y * 64;
  f32x4 acc[2][4] = {};
  for (int k0 = 0; k0 < K; k0 += 64) {
#pragma unroll
    for (int p = 0; p < 4; ++p) {
      int c = tid + p * 256;            // 1024 chunks of 16B (A tile)
      int r = c >> 3, sl = c & 7;
      __builtin_amdgcn_global_load_lds(
          (__attribute__((address_space(1))) void*)(A + (size_t)(m0 + r) * K + k0 + ((sl ^ (r & 7)) << 3)),
          (__attribute__((address_space(3))) void*)(Al + c * 8), 16, 0, 0);
    }
#pragma unroll
    for (int p = 0; p < 2; ++p) {
      int c = tid + p * 256;            // 512 chunks of 16B (B tile)
      int r = c >> 3, sl = c & 7;
      __builtin_amdgcn_global_load_lds(
          (__attribute__((address_space(1))) void*)(Bt + (size_t)(n0 + r) * K + k0 + ((sl ^ (r & 7)) << 3)),
          (__attribute__((address_space(3))) void*)(Bl + c * 8), 16, 0, 0);
    }
    __syncthreads();
#pragma unroll
    for (int kk = 0; kk < 2; ++kk) {
      bfrag a[2], b[4];
#pragma unroll
      for (int mi = 0; mi < 2; ++mi) {
        int row = wid * 32 + mi * 16 + l16;
        a[mi] = *reinterpret_cast<const bfrag*>(
            Al + row * 64 + ((((kk << 2) | lg) ^ (l16 & 7)) << 3));
      }
#pragma unroll
      for (int ni = 0; ni < 4; ++ni) {
        int row = ni * 16 + l16;
        b[ni] = *reinterpret_cast<const bfrag*>(
            Bl + row * 64 + ((((kk << 2) | lg) ^ (l16 & 7)) << 3));
      }
#pragma unroll
      for (int mi = 0; mi < 2; ++mi)
#pragma unroll
        for (int ni = 0; ni < 4; ++ni)
          acc[mi][ni] = __builtin_amdgcn_mfma_f32_16x16x32_bf16(a[mi], b[ni], acc[mi][ni], 0, 0, 0);
    }
    __syncthreads();
  }
#pragma unroll
  for (int mi = 0; mi < 2; ++mi)
#pragma unroll
    for (int ni = 0; ni < 4; ++ni) {
      int col = n0 + ni * 16 + l16;
      float bb = bias[col];
#pragma unroll
      for (int r = 0; r < 4; ++r) {
        int row = m0 + wid * 32 + mi * 16 + lg * 4 + r;
        float v = acc[mi][ni][r] + bb;
        if (STORE_BF16) ((u16*)Cout)[(size_t)row * N + col] = f2bf(v);
        else            ((float*)Cout)[(size_t)row * N + col] = v;
      }
    }
}

// ---------- flash attention v4: 32x32 MFMA, 32 q-rows/wave, lane-local softmax ----------
// grid (S/64, NHEAD, B), 2 waves x 32 q. Swapped both ways:
//   QK^T: D[kv][q] = mfma(A=K, B=Q)  -> col q = lane&31, row kv = crow(r,hi)
//   PV:   O^T[d][q] = mfma(A=V^T, B=P) -> col q = lane&31, row d = crow(r,hi)
// crow(r,hi) = (r&3) + 8*(r>>2) + 4*hi  [guide-verified 32x32 C/D layout].
// All softmax state (m, l, alpha) lives at q = lane&31: one shfl_xor(32) per
// reduce, zero redistribution shuffles. K staged in LDS (dbuf, XOR swizzle,
// staged at iter top -> full-iter latency slack, ONE barrier/iter).
// P roundtrip via wave-private LDS: write [q][32t+crow], read B-frag [q][16ks+8hi].
__global__ __launch_bounds__(128, 2) void k_attn(const u16* __restrict__ QKV,
                                                 const u16* __restrict__ Vt,
                                                 const float* __restrict__ Mbias,
                                                 u16* __restrict__ ctx) {
  __shared__ __align__(16) u16 Kl[2][64 * 64];   // 16 KB, chunk cb at slot cb^(row&7)
  __shared__ __align__(16) u16 Pl[2][32][72];    // 9 KB, wave-private P
  const int tid = threadIdx.x;
  const int lane = tid & 63, l32 = lane & 31, hi = lane >> 5, wid = tid >> 6;
  const int qw = blockIdx.x * 64 + wid * 32;
  const int h = blockIdx.y, b = blockIdx.z;

  // Q B-frags: B[k][q]: q = l32, d = ds*16 + 8*hi + j
  const u16* Qrow = QKV + (size_t)(b * SEQ + qw + l32) * NQKV + h * 64;
  bfrag Qf[4];
#pragma unroll
  for (int ds = 0; ds < 4; ++ds)
    Qf[ds] = *reinterpret_cast<const bfrag*>(Qrow + ds * 16 + 8 * hi);

  const u16* Vb = Vt + (size_t)b * 64 * SEQ;
  const u16* Kg = QKV + (size_t)b * SEQ * NQKV + HID;  // K rows, stride NQKV
  const float* mb = Mbias + b * SEQ;

  auto stage_k = [&](int buf, int kv) {
#pragma unroll
    for (int hh = 0; hh < 4; ++hh) {
      int c = tid + hh * 128;                 // 512 chunks of 16B
      int r = c >> 3, cb = (c & 7) ^ (r & 7); // linear LDS dest, inv-swizzled source
      __builtin_amdgcn_global_load_lds(
          (__attribute__((address_space(1))) void*)(Kg + (size_t)(kv + r) * NQKV + cb * 8),
          (__attribute__((address_space(3))) void*)(&Kl[buf][c * 8]), 16, 0, 0);
    }
  };

  stage_k(0, 0);
  __syncthreads();  // drains vmcnt -> K buf0 visible

  float mrun = -1e30f, lrun = 0.0f;  // softmax state for q = qw + l32
  f32x16 accO0 = {}, accO1 = {};     // O^T[d][q]: d = dt*32 + crow(r,hi), q = l32

  for (int it = 0; it < SEQ / 64; ++it) {
    const int kv0 = it * 64, cur = it & 1;
    if (it + 1 < SEQ / 64) stage_k(cur ^ 1, kv0 + 64);  // full iter of slack

    // V^T A-frags, d-tile 0: A[d=l32][kv = ks*16 + 8hi + j]
    bfrag Vf0[4];
#pragma unroll
    for (int ks = 0; ks < 4; ++ks)
      Vf0[ks] = *reinterpret_cast<const bfrag*>(
          Vb + (size_t)l32 * SEQ + kv0 + ks * 16 + 8 * hi);

    // QK^T: two 32-kv tiles from Kl[cur]
    f32x16 p0 = {}, p1 = {};
#pragma unroll
    for (int ds = 0; ds < 4; ++ds) {
      const int slot = (2 * ds + hi) ^ (l32 & 7);
      bfrag k0 = *reinterpret_cast<const bfrag*>(&Kl[cur][l32 * 64 + (slot << 3)]);
      bfrag k1 = *reinterpret_cast<const bfrag*>(&Kl[cur][(32 + l32) * 64 + (slot << 3)]);
      p0 = __builtin_amdgcn_mfma_f32_32x32x16_bf16(k0, Qf[ds], p0, 0, 0, 0);
      p1 = __builtin_amdgcn_mfma_f32_32x32x16_bf16(k1, Qf[ds], p1, 0, 0, 0);
    }

    // scale + mask bias: kv = kv0 + 32t + (r&3) + 8*(r>>2) + 4*hi
#pragma unroll
    for (int rq = 0; rq < 4; ++rq) {
      f32x4 m0 = *reinterpret_cast<const f32x4*>(&mb[kv0 + 8 * rq + 4 * hi]);
      f32x4 m1 = *reinterpret_cast<const f32x4*>(&mb[kv0 + 32 + 8 * rq + 4 * hi]);
#pragma unroll
      for (int r2 = 0; r2 < 4; ++r2) {
        p0[rq * 4 + r2] = p0[rq * 4 + r2] * 0.125f + m0[r2];
        p1[rq * 4 + r2] = p1[rq * 4 + r2] * 0.125f + m1[r2];
      }
    }

    // max over 64 kv: 31 in-lane + ONE shfl_xor(32)
    float tmax = fmaxf(p0[0], p1[0]);
#pragma unroll
    for (int r = 1; r < 16; ++r) tmax = fmaxf(tmax, fmaxf(p0[r], p1[r]));
    tmax = fmaxf(tmax, __shfl_xor(tmax, 32));

    // defer-max (T13): all state lane-local, no redistribution
    if (!__all(tmax - mrun <= 8.0f)) {
      float mnew = fmaxf(mrun, tmax);
      float alpha = __expf(mrun - mnew);
      mrun = mnew;
      lrun *= alpha;
#pragma unroll
      for (int r = 0; r < 16; ++r) { accO0[r] *= alpha; accO1[r] *= alpha; }
    }

    // exp + row-sum
    float rsum = 0.0f;
#pragma unroll
    for (int r = 0; r < 16; ++r) {
      p0[r] = __expf(p0[r] - mrun);
      p1[r] = __expf(p1[r] - mrun);
      rsum += p0[r] + p1[r];
    }
    rsum += __shfl_xor(rsum, 32);
    lrun += rsum;

    // P -> LDS (wave-private): [q=l32][32t + 8rq + 4hi + r2]
#pragma unroll
    for (int rq = 0; rq < 4; ++rq) {
      uint2 w0, w1;
      w0.x = cvtpk_bf16(p0[rq * 4 + 0], p0[rq * 4 + 1]);
      w0.y = cvtpk_bf16(p0[rq * 4 + 2], p0[rq * 4 + 3]);
      w1.x = cvtpk_bf16(p1[rq * 4 + 0], p1[rq * 4 + 1]);
      w1.y = cvtpk_bf16(p1[rq * 4 + 2], p1[rq * 4 + 3]);
      *reinterpret_cast<uint2*>(&Pl[wid][l32][8 * rq + 4 * hi]) = w0;
      *reinterpret_cast<uint2*>(&Pl[wid][l32][32 + 8 * rq + 4 * hi]) = w1;
    }

    // V^T A-frags, d-tile 1 (issued here: latency hides under PV of tile 0)
    bfrag Vf1[4];
#pragma unroll
    for (int ks = 0; ks < 4; ++ks)
      Vf1[ks] = *reinterpret_cast<const bfrag*>(
          Vb + (size_t)(32 + l32) * SEQ + kv0 + ks * 16 + 8 * hi);

    // PV: O^T[d][q] += V^T[d][kv] * P[kv][q]; B-frag P: [q=l32][kv=ks*16+8hi+j]
#pragma unroll
    for (int ks = 0; ks < 4; ++ks) {
      bfrag Pf = *reinterpret_cast<const bfrag*>(&Pl[wid][l32][ks * 16 + 8 * hi]);
      accO0 = __builtin_amdgcn_mfma_f32_32x32x16_bf16(Vf0[ks], Pf, accO0, 0, 0, 0);
      accO1 = __builtin_amdgcn_mfma_f32_32x32x16_bf16(Vf1[ks], Pf, accO1, 0, 0, 0);
    }
    __syncthreads();  // WAR: Kl[cur] reads done before next restage; RAW: staged visible
  }

  // epilogue: ctx[q][h*64 + d], d = dt*32 + 8rq + 4hi + r2, all lane-local
  float linv = 1.0f / lrun;
  size_t base = (size_t)(b * SEQ + qw + l32) * HID + h * 64;
#pragma unroll
  for (int rq = 0; rq < 4; ++rq) {
    uint2 w0, w1;
    w0.x = cvtpk_bf16(accO0[rq * 4 + 0] * linv, accO0[rq * 4 + 1] * linv);
    w0.y = cvtpk_bf16(accO0[rq * 4 + 2] * linv, accO0[rq * 4 + 3] * linv);
    w1.x = cvtpk_bf16(accO1[rq * 4 + 0] * linv, accO1[rq * 4 + 1] * linv);
    w1.y = cvtpk_bf16(accO1[rq * 4 + 2] * linv, accO1[rq * 4 + 3] * linv);
    *reinterpret_cast<uint2*>(&ctx[base + 8 * rq + 4 * hi]) = w0;
    *reinterpret_cast<uint2*>(&ctx[base + 32 + 8 * rq + 4 * hi]) = w1;
  }
}

extern "C" void kernel_launch(void* const* d_in, const int* in_sizes, int n_in,
                              void* d_out, int out_size, void* d_ws, size_t ws_size,
                              hipStream_t stream) {
  const float* x  = (const float*)d_in[0];
  const int* am   = (const int*)d_in[1];
  const float* Wq = (const float*)d_in[2];
  const float* bq = (const float*)d_in[3];
  const float* Wk = (const float*)d_in[4];
  const float* bk = (const float*)d_in[5];
  const float* Wv = (const float*)d_in[6];
  const float* bv = (const float*)d_in[7];
  const float* Wo = (const float*)d_in[8];
  const float* bo = (const float*)d_in[9];

  char* ws = (char*)d_ws;
  u16*  Xb     = (u16*)(ws + 0);          //  8.00 MB  [4096][1024]
  u16*  Wt_qkv = (u16*)(ws + 8388608);    //  2.25 MB  [1152][1024]
  u16*  Wt_o   = (u16*)(ws + 10747904);   //  2.00 MB  [1024][1024]
  float* bqkv  = (float*)(ws + 12845056); //  4.5 KB
  float* Mbias = (float*)(ws + 12849664); // 16 KB    [2][2048]
  u16*  QKV    = (u16*)(ws + 12866048);   //  9.00 MB  [4096][1152]
  u16*  Vt     = (u16*)(ws + 22303232);   //  0.50 MB  [2][64][2048]
  u16*  ctx    = (u16*)(ws + 22827520);   //  8.00 MB  [4096][1024]

  k_cvt_x<<<4096, 256, 0, stream>>>(x, Xb);
  k_tr<<<dim3(16, 16), 256, 0, stream>>>(Wq, 1024, Wt_qkv, 0);
  k_tr<<<dim3(16, 1), 256, 0, stream>>>(Wk, 64, Wt_qkv, 1024);
  k_tr<<<dim3(16, 1), 256, 0, stream>>>(Wv, 64, Wt_qkv, 1088);
  k_tr<<<dim3(16, 16), 256, 0, stream>>>(Wo, 1024, Wt_o, 0);
  k_bias<<<5, 256, 0, stream>>>(bq, bk, bv, bqkv);
  k_mb<<<16, 256, 0, stream>>>(am, Mbias);

  dim3 g1(32, 18);
  k_gemm<1><<<g1, 256, 0, stream>>>(Xb, Wt_qkv, bqkv, (void*)QKV, MROWS, NQKV, HID);

  k_vt<<<dim3(32, 2), 256, 0, stream>>>(QKV, Vt);

  dim3 g2(SEQ / 64, NHEAD, 2);
  k_attn<<<g2, 128, 0, stream>>>(QKV, Vt, Mbias, ctx);

  dim3 g3(32, 16);
  k_gemm<0><<<g3, 256, 0, stream>>>(ctx, Wt_o, bo, d_out, MROWS, HID, HID);
}